// Round 3
// baseline (325.144 us; speedup 1.0000x reference)
//
#include <hip/hip_runtime.h>

#define B_  4
#define C_  64
#define H_  256
#define W_  256
#define HW_ 65536
#define NPIX_ (B_*HW_)        /* 262144 */
#define NELEM_ (B_*C_*HW_)    /* 16777216 */

#define OMS 200     /* bf16 om row stride in LDS (400B: 16B-aligned) */
#define TS  72      /* bf16 sval row stride in LDS (144B: 16B-aligned) */

typedef __attribute__((ext_vector_type(8))) short short8;
typedef __attribute__((ext_vector_type(4))) float floatx4;

static __device__ __forceinline__ unsigned short f2bf(float f){
  unsigned u = __float_as_uint(f);
  u += 0x7fff + ((u >> 16) & 1);          // RNE
  return (unsigned short)(u >> 16);
}
static __device__ __forceinline__ float bf2f(unsigned short s){
  return __uint_as_float(((unsigned)s) << 16);
}
static __device__ __forceinline__ unsigned pack2(float a, float b){
  return (unsigned)f2bf(a) | ((unsigned)f2bf(b) << 16);
}

// ---------------- K0a: convert pw(192x64) + w2(64x64) to bf16 ---------------
__global__ __launch_bounds__(256) void k_cvtw(
    const float* __restrict__ pw, const float* __restrict__ w2,
    unsigned short* __restrict__ wB)   // [0,12288): pwB, [12288,16384): w2B
{
  int i = blockIdx.x*256 + threadIdx.x;
  wB[i] = f2bf(i < 12288 ? pw[i] : w2[i - 12288]);
}

// ---------------- K1: dwconv 3x3 on fp32 x -> t bf16; also emits xB ---------
// (k_cvtx fused away: the center tap of the 3x3 window IS x[c][h][w], so each
// thread writes its 16 channels' center taps as bf16 to xB.)
__global__ __launch_bounds__(256) void k_dwconv(
    const float* __restrict__ x,
    const float* __restrict__ dwW,
    unsigned short* __restrict__ xB,
    unsigned short* __restrict__ t)
{
  int tid = threadIdx.x;
  int bid = ((blockIdx.x & 7) << 9) + (blockIdx.x >> 3);   // XCD-contiguous
  int b    = bid >> 10;
  int tile = bid & 1023;
  int h    = tile >> 2;
  int w0   = (tile & 3) << 6;
  int p  = tid & 63;
  int cg = tid >> 6;
  int wg = w0 + p;

  unsigned pk[8];
#pragma unroll
  for (int i = 0; i < 16; ++i){
    int c = cg*16 + i;
    const float* xp = x + ((size_t)(b*C_ + c) << 16);
    const float* wp = dwW + c*9;                 // wave-uniform -> scalar loads
    float acc = 0.f;
    float ctr = 0.f;
#pragma unroll
    for (int dy = -1; dy <= 1; ++dy){
      int hy = h + dy;
      if ((unsigned)hy >= (unsigned)H_) continue;
      const float* row = xp + (hy << 8);
#pragma unroll
      for (int dx = -1; dx <= 1; ++dx){
        int wx = wg + dx;
        if ((unsigned)wx >= (unsigned)W_) continue;
        float v = row[wx];
        if (dy == 0 && dx == 0) ctr = v;
        acc += wp[(dy+1)*3 + (dx+1)] * v;
      }
    }
    xB[((size_t)(b*C_ + c) << 16) + (h << 8) + wg] = f2bf(ctr);
    unsigned short bv = f2bf(acc);
    if (i & 1) pk[i>>1] |= ((unsigned)bv << 16);
    else       pk[i>>1]  = (unsigned)bv;
  }
  size_t rowbase = ((size_t)bid*64 + p)*64 + cg*16;
  uint4 u0; u0.x = pk[0]; u0.y = pk[1]; u0.z = pk[2]; u0.w = pk[3];
  uint4 u1; u1.x = pk[4]; u1.y = pk[5]; u1.z = pk[6]; u1.w = pk[7];
  *(uint4*)(t + rowbase)     = u0;
  *(uint4*)(t + rowbase + 8) = u1;
}

// ---------------- K2: fused GEMM1 -> sample -> GEMM2 (+BN partials) ---------
// om and sval live only in LDS. Channel mapping: sy=om[2c], sx=om[2c+1],
// modulator=om[128+c]. Bias dropped (cancels in BN exactly).
// Phase B lane map: pl=tid&63, cg=tid>>6 -> a coalescing quad holds 4 ADJACENT
// PIXELS of the SAME channel plane (offsets are typically tiny, so the quad's
// gather addresses share 1-2 cache lines instead of 4 planes 2MB apart).
__global__ __launch_bounds__(256, 5) void k_fuse(
    const unsigned short* __restrict__ xB,
    const unsigned short* __restrict__ t,
    const unsigned short* __restrict__ pwB,
    const unsigned short* __restrict__ w2B,
    unsigned short* __restrict__ outB,
    float* __restrict__ gsumS,
    float* __restrict__ gsqS)
{
  __shared__ __align__(16) char lds[25600];
  unsigned short* OM = (unsigned short*)lds;        // 64 x OMS bf16 (25600 B)
  unsigned short* T  = (unsigned short*)lds;        // 64 x TS bf16 (overlays OM)
  float* red1 = (float*)(lds + 9216);               // 4 x 64 (overlays dead OM tail)
  float* red2 = (float*)(lds + 10240);              // 4 x 64

  int tid = threadIdx.x;
  int bid = ((blockIdx.x & 7) << 9) + (blockIdx.x >> 3);   // XCD-contiguous
  int wv = tid >> 6, lane = tid & 63;
  int mrow = lane & 15, q = lane >> 4;
  int px0 = bid*64;
  int pxw = px0 + wv*16;        // wave's pixel base (16 px per wave)

  // ---- phase A: GEMM1  om[px][ch] = sum_c t[px][c]*pw[ch][c] ----
  short8 bfrag[2];
#pragma unroll
  for (int kb = 0; kb < 2; ++kb)
    bfrag[kb] = *(const short8*)(t + (size_t)(pxw + mrow)*64 + kb*32 + q*8);

  floatx4 acc[12];
#pragma unroll
  for (int mt = 0; mt < 12; ++mt) acc[mt] = (floatx4){0.f,0.f,0.f,0.f};
#pragma unroll
  for (int kb = 0; kb < 2; ++kb)
#pragma unroll
    for (int mt = 0; mt < 12; ++mt){
      short8 af = *(const short8*)(pwB + (mt*16 + mrow)*64 + kb*32 + q*8);
      acc[mt] = __builtin_amdgcn_mfma_f32_16x16x32_bf16(af, bfrag[kb], acc[mt], 0, 0, 0);
    }

  {
    int omrow = (wv*16 + mrow)*OMS;
#pragma unroll
    for (int mt = 0; mt < 12; ++mt){
      uint2 u; u.x = pack2(acc[mt][0], acc[mt][1]); u.y = pack2(acc[mt][2], acc[mt][3]);
      *(uint2*)(OM + omrow + mt*16 + q*4) = u;
    }
  }
  __syncthreads();

  // ---- phase B: deformable bilinear sampling from bf16 x ----
  unsigned pk[8];
  {
    int pl = tid & 63;          // block-local pixel   (quad = 4 adjacent px)
    int cg = tid >> 6;          // channel group       (wave-uniform)
    int px = px0 + pl;
    int b = px >> 16;
    int p = px & (HW_-1);
    int h = p >> 8, w = p & (W_-1);

    const char* xbyte = (const char*)(xB + ((size_t)(b*C_ + cg*16) << 16));
    float hf = (float)h, wf = (float)w;

    float rw0[8], rw1[8], cwA[8], cwB[8];
    unsigned pu0[8], pu1[8];

#pragma unroll
    for (int half = 0; half < 2; ++half){
      const uint4* ob = (const uint4*)(OM + pl*OMS + cg*32 + half*16);
      uint4 oA = ob[0], oB = ob[1];
      uint4 mv = *(const uint4*)(OM + pl*OMS + 128 + cg*16 + half*8);
      unsigned pr[8] = {oA.x,oA.y,oA.z,oA.w, oB.x,oB.y,oB.z,oB.w};
      unsigned md4[4] = {mv.x,mv.y,mv.z,mv.w};

      // ---- stage: addresses + weights, issue the 16 loads ----
#pragma unroll
      for (int i = 0; i < 8; ++i){
        unsigned pair = pr[i];
        float oy = __uint_as_float(pair << 16);
        float ox = __uint_as_float(pair & 0xffff0000u);
        float mm = __uint_as_float((i & 1) ? (md4[i>>1] & 0xffff0000u)
                                           : (md4[i>>1] << 16));
        float mod = 2.f / (1.f + __expf(-mm));
        oy = fminf(fmaxf(oy, -64.f), 64.f);
        ox = fminf(fmaxf(ox, -64.f), 64.f);
        float sy = hf + oy, sx = wf + ox;
        float y0f = floorf(sy), x0f = floorf(sx);
        float wy = sy - y0f, wxr = sx - x0f;
        int y0 = (int)y0f, x0 = (int)x0f;
        int yc0 = min(max(y0,     0), 255);
        int yc1 = min(max(y0 + 1, 0), 255);    // clamp AFTER increment
        int xc  = min(max(x0, 0), 254);        // pair start (always in-plane)
        bool y0v = ((unsigned)y0       < 256u);
        bool y1v = ((unsigned)(y0 + 1) < 256u);
        bool x0v = ((unsigned)x0       < 256u);
        bool x1v = ((unsigned)(x0 + 1) < 256u);
        bool x0lo = (x0 == xc);
        float r0 = y0v ? (1.f - wy) * mod : 0.f;
        float r1 = y1v ? wy * mod : 0.f;
        float c0w = x0v ? (1.f - wxr) : 0.f;
        float c1w = x1v ? wxr : 0.f;
        rw0[i] = r0; rw1[i] = r1;
        cwA[i] = x0lo ? c0w : c1w;             // weight on value at xc
        cwB[i] = x0lo ? c1w : c0w;             // weight on value at xc+1
        unsigned cb  = ((unsigned)(half*8 + i)) << 17;   // channel byte offset
        unsigned o0  = cb + ((unsigned)yc0 << 9) + ((unsigned)xc << 1);
        unsigned o1  = cb + ((unsigned)yc1 << 9) + ((unsigned)xc << 1);
        __builtin_memcpy(&pu0[i], xbyte + o0, 4);   // (y0 row, x: xc..xc+1)
        __builtin_memcpy(&pu1[i], xbyte + o1, 4);   // (y0+1 row, same)
      }
      // ---- consume ----
#pragma unroll
      for (int i = 0; i < 8; ++i){
        int ci = half*8 + i;
        float lo0 = __uint_as_float(pu0[i] << 16);
        float hi0 = __uint_as_float(pu0[i] & 0xffff0000u);
        float lo1 = __uint_as_float(pu1[i] << 16);
        float hi1 = __uint_as_float(pu1[i] & 0xffff0000u);
        float sres = rw0[i] * (cwA[i]*lo0 + cwB[i]*hi0)
                   + rw1[i] * (cwA[i]*lo1 + cwB[i]*hi1);
        unsigned short bv = f2bf(sres);
        if (ci & 1) pk[ci>>1] |= ((unsigned)bv << 16);
        else        pk[ci>>1]  = (unsigned)bv;
      }
    }
  }
  __syncthreads();              // all OM reads done before T overlays it

  {
    int pl = tid & 63, cg = tid >> 6;
    uint4 u0; u0.x = pk[0]; u0.y = pk[1]; u0.z = pk[2]; u0.w = pk[3];
    uint4 u1; u1.x = pk[4]; u1.y = pk[5]; u1.z = pk[6]; u1.w = pk[7];
    *(uint4*)(T + pl*TS + cg*16)     = u0;
    *(uint4*)(T + pl*TS + cg*16 + 8) = u1;
  }
  __syncthreads();

  // ---- phase C: GEMM2  out[px][och] = sum_c sval[px][c]*w2[och][c] ----
  short8 a2[2];
#pragma unroll
  for (int kb = 0; kb < 2; ++kb)
    a2[kb] = *(const short8*)(T + (wv*16 + mrow)*TS + kb*32 + q*8);

  floatx4 acc2[4];
#pragma unroll
  for (int nt = 0; nt < 4; ++nt) acc2[nt] = (floatx4){0.f,0.f,0.f,0.f};
#pragma unroll
  for (int kb = 0; kb < 2; ++kb)
#pragma unroll
    for (int nt = 0; nt < 4; ++nt){
      short8 bf = *(const short8*)(w2B + (nt*16 + mrow)*64 + kb*32 + q*8);
      acc2[nt] = __builtin_amdgcn_mfma_f32_16x16x32_bf16(a2[kb], bf, acc2[nt], 0, 0, 0);
    }

  int b   = pxw >> 16;
  int hw0 = pxw & (HW_-1);
#pragma unroll
  for (int nt = 0; nt < 4; ++nt){
    int och = nt*16 + mrow;
    float a0 = acc2[nt][0], a1 = acc2[nt][1], a2v = acc2[nt][2], a3 = acc2[nt][3];
    uint2 u; u.x = pack2(a0, a1); u.y = pack2(a2v, a3);
    *(uint2*)(outB + ((size_t)(b*C_ + och) << 16) + hw0 + q*4) = u;
    float s1 = a0 + a1 + a2v + a3;
    float s2 = a0*a0 + a1*a1 + a2v*a2v + a3*a3;
    s1 += __shfl_xor(s1, 16, 64);  s2 += __shfl_xor(s2, 16, 64);
    s1 += __shfl_xor(s1, 32, 64);  s2 += __shfl_xor(s2, 32, 64);
    if (q == 0){ red1[wv*64 + och] = s1; red2[wv*64 + och] = s2; }
  }
  __syncthreads();
  if (tid < 64){
    float t1 = red1[tid] + red1[64+tid] + red1[128+tid] + red1[192+tid];
    float t2 = red2[tid] + red2[64+tid] + red2[128+tid] + red2[192+tid];
    int slot = blockIdx.x & 31;
    atomicAdd(&gsumS[slot*64 + tid], t1);
    atomicAdd(&gsqS[slot*64 + tid], t2);
  }
}

// ---------------- finalize BN stats into scale/shift ------------------------
__global__ void k_finalize(const float* __restrict__ gsumS, const float* __restrict__ gsqS,
                           const float* __restrict__ gamma, const float* __restrict__ beta,
                           float* __restrict__ scale, float* __restrict__ shift)
{
  int o = threadIdx.x;
  if (o < 64){
    float s1 = 0.f, s2 = 0.f;
    for (int s = 0; s < 32; ++s){ s1 += gsumS[s*64 + o]; s2 += gsqS[s*64 + o]; }
    float n = (float)NPIX_;
    float mean = s1 / n;
    float var  = s2 / n - mean*mean;          // biased, matches jnp.var
    float sc = gamma[o] * rsqrtf(var + 1e-5f);
    scale[o] = sc;
    shift[o] = beta[o] - mean*sc;
  }
}

// ---------------- K5: BN apply + exact GELU, 8 elems/thread -----------------
__global__ __launch_bounds__(256) void k_bn_gelu(
    const uint4* __restrict__ outB4,   // 8 bf16
    const float* __restrict__ scale,
    const float* __restrict__ shift,
    float4* __restrict__ y4)
{
  int i = blockIdx.x*256 + threadIdx.x;           // over NELEM_/8
  int och = (i >> 13) & 63;                       // (8i >> 16) & 63
  float sc = scale[och], sh = shift[och];
  uint4 u = outB4[i];
  float e[8];
  e[0] = bf2f((unsigned short)(u.x & 0xffffu)); e[1] = bf2f((unsigned short)(u.x >> 16));
  e[2] = bf2f((unsigned short)(u.y & 0xffffu)); e[3] = bf2f((unsigned short)(u.y >> 16));
  e[4] = bf2f((unsigned short)(u.z & 0xffffu)); e[5] = bf2f((unsigned short)(u.z >> 16));
  e[6] = bf2f((unsigned short)(u.w & 0xffffu)); e[7] = bf2f((unsigned short)(u.w >> 16));
  float4 o0, o1;
  float a;
  a = e[0]*sc + sh; o0.x = 0.5f*a*(1.f + erff(a*0.70710678118654752f));
  a = e[1]*sc + sh; o0.y = 0.5f*a*(1.f + erff(a*0.70710678118654752f));
  a = e[2]*sc + sh; o0.z = 0.5f*a*(1.f + erff(a*0.70710678118654752f));
  a = e[3]*sc + sh; o0.w = 0.5f*a*(1.f + erff(a*0.70710678118654752f));
  a = e[4]*sc + sh; o1.x = 0.5f*a*(1.f + erff(a*0.70710678118654752f));
  a = e[5]*sc + sh; o1.y = 0.5f*a*(1.f + erff(a*0.70710678118654752f));
  a = e[6]*sc + sh; o1.z = 0.5f*a*(1.f + erff(a*0.70710678118654752f));
  a = e[7]*sc + sh; o1.w = 0.5f*a*(1.f + erff(a*0.70710678118654752f));
  y4[2*i]   = o0;
  y4[2*i+1] = o1;
}

extern "C" void kernel_launch(void* const* d_in, const int* in_sizes, int n_in,
                              void* d_out, int out_size, void* d_ws, size_t ws_size,
                              hipStream_t stream)
{
  (void)in_sizes; (void)n_in; (void)out_size; (void)ws_size;
  const float* x     = (const float*)d_in[0];
  const float* dw    = (const float*)d_in[1];
  const float* pw    = (const float*)d_in[2];
  const float* w2    = (const float*)d_in[3];
  /* d_in[4] = bias: cancels exactly in BN (mean-subtracted), unused */
  const float* gamma = (const float*)d_in[5];
  const float* beta  = (const float*)d_in[6];

  // ws layout:
  //   [0,          33554432)  xB    bf16 x
  //   [33554432,   67108864)  t     bf16 dwconv out [px][c]
  //   [67108864,  100663296)  outB  bf16 conv2 out, och-major
  //   [100663296, 100680192)  stats (gsumS 8K, gsqS 8K, scale/shift)
  //   [100680192, 100712960)  wB    bf16 weights (pw 24K, w2 8K)
  char* ws = (char*)d_ws;
  unsigned short* xB    = (unsigned short*)ws;
  unsigned short* t     = (unsigned short*)(ws + 33554432);
  unsigned short* outB  = (unsigned short*)(ws + 67108864);
  float*          stats = (float*)(ws + 100663296);
  float* gsumS = stats;                 // 32 slots x 64
  float* gsqS  = stats + 2048;
  float* scale = stats + 4096;
  float* shift = stats + 4160;
  unsigned short* wB  = (unsigned short*)(ws + 100680192);
  unsigned short* pwB = wB;
  unsigned short* w2B = wB + 12288;

  k_cvtw    <<<64, 256, 0, stream>>>(pw, w2, wB);
  hipMemsetAsync(stats, 0, 16384, stream);        // zero gsum/gsq slots
  k_dwconv  <<<NPIX_/64, 256, 0, stream>>>(x, dw, xB, t);
  k_fuse    <<<NPIX_/64, 256, 0, stream>>>(xB, t, pwB, w2B, outB, gsumS, gsqS);
  k_finalize<<<1, 64, 0, stream>>>(gsumS, gsqS, gamma, beta, scale, shift);
  k_bn_gelu <<<NELEM_/8/256, 256, 0, stream>>>((const uint4*)outB, scale, shift,
                                               (float4*)d_out);
}

// Round 4
// 294.983 us; speedup vs baseline: 1.1022x; 1.1022x over previous
//
#include <hip/hip_runtime.h>

#define B_  4
#define C_  64
#define H_  256
#define W_  256
#define HW_ 65536
#define NPIX_ (B_*HW_)        /* 262144 */
#define NELEM_ (B_*C_*HW_)    /* 16777216 */

#define OMS 200     /* bf16 om row stride in LDS (400B: 16B-aligned) */
#define TS  72      /* bf16 sval row stride in LDS (144B: 16B-aligned) */

typedef __attribute__((ext_vector_type(8))) short short8;
typedef __attribute__((ext_vector_type(4))) float floatx4;

static __device__ __forceinline__ unsigned short f2bf(float f){
  unsigned u = __float_as_uint(f);
  u += 0x7fff + ((u >> 16) & 1);          // RNE
  return (unsigned short)(u >> 16);
}
static __device__ __forceinline__ float bf2f(unsigned short s){
  return __uint_as_float(((unsigned)s) << 16);
}
static __device__ __forceinline__ unsigned pack2(float a, float b){
  return (unsigned)f2bf(a) | ((unsigned)f2bf(b) << 16);
}

// ---------------- K0a: convert pw(192x64) + w2(64x64) to bf16 ---------------
__global__ __launch_bounds__(256) void k_cvtw(
    const float* __restrict__ pw, const float* __restrict__ w2,
    unsigned short* __restrict__ wB)   // [0,12288): pwB, [12288,16384): w2B
{
  int i = blockIdx.x*256 + threadIdx.x;
  wB[i] = f2bf(i < 12288 ? pw[i] : w2[i - 12288]);
}

// ---------------- K1: dwconv 3x3 on fp32 x -> t bf16; also emits xB ---------
// Branchless: all loads from clamped addresses (always valid); zero-padding
// restored by folding row-validity into scalar weights and col-validity into
// per-lane cndmask on values. Loads staged in 4-channel batches (36 deep MLP).
__global__ __launch_bounds__(256) void k_dwconv(
    const float* __restrict__ x,
    const float* __restrict__ dwW,
    unsigned short* __restrict__ xB,
    unsigned short* __restrict__ t)
{
  int tid = threadIdx.x;
  int bid = ((blockIdx.x & 7) << 9) + (blockIdx.x >> 3);   // XCD-contiguous
  int b    = bid >> 10;
  int tile = bid & 1023;
  int h    = tile >> 2;
  int w0   = (tile & 3) << 6;
  int p  = tid & 63;
  int cg = tid >> 6;
  int wg = w0 + p;

  // clamped row bases (h block-uniform -> scalar), validity as weight scale
  int rm = (h > 0   ? h-1 : 0) << 8;
  int r0 = h << 8;
  int rp = (h < 255 ? h+1 : 255) << 8;
  float vm = (h > 0)   ? 1.f : 0.f;
  float vp = (h < 255) ? 1.f : 0.f;
  // clamped col offsets (per-lane, once)
  int wl = wg > 0   ? wg-1 : 0;
  int wr = wg < 255 ? wg+1 : 255;
  bool ml = (wg > 0);
  bool mr = (wg < 255);

  // 9 tap offsets (elements) within a plane, shared across channels
  int o0 = rm + wl, o1 = rm + wg, o2 = rm + wr;
  int o3 = r0 + wl, o4 = r0 + wg, o5 = r0 + wr;
  int o6 = rp + wl, o7 = rp + wg, o8 = rp + wr;

  const float* plane0 = x + ((size_t)(b*C_ + cg*16) << 16);

  unsigned pk[8];
#pragma unroll
  for (int ib = 0; ib < 4; ++ib){       // 4 batches of 4 channels
    float v[4][9];
    // ---- stage: 36 independent loads ----
#pragma unroll
    for (int j = 0; j < 4; ++j){
      const float* pl = plane0 + ((size_t)(ib*4 + j) << 16);
      v[j][0] = pl[o0]; v[j][1] = pl[o1]; v[j][2] = pl[o2];
      v[j][3] = pl[o3]; v[j][4] = pl[o4]; v[j][5] = pl[o5];
      v[j][6] = pl[o6]; v[j][7] = pl[o7]; v[j][8] = pl[o8];
    }
    // ---- consume ----
#pragma unroll
    for (int j = 0; j < 4; ++j){
      int i = ib*4 + j;
      int c = cg*16 + i;
      const float* wp = dwW + c*9;       // wave-uniform -> scalar loads
      float w00 = wp[0]*vm, w01 = wp[1]*vm, w02 = wp[2]*vm;
      float w20 = wp[6]*vp, w21 = wp[7]*vp, w22 = wp[8]*vp;
      float l0 = ml ? v[j][0] : 0.f, g0 = mr ? v[j][2] : 0.f;
      float l1 = ml ? v[j][3] : 0.f, g1 = mr ? v[j][5] : 0.f;
      float l2 = ml ? v[j][6] : 0.f, g2 = mr ? v[j][8] : 0.f;
      float acc = w00*l0 + w01*v[j][1] + w02*g0
                + wp[3]*l1 + wp[4]*v[j][4] + wp[5]*g1
                + w20*l2 + w21*v[j][7] + w22*g2;
      xB[((size_t)(b*C_ + c) << 16) + r0 + wg] = f2bf(v[j][4]);
      unsigned short bv = f2bf(acc);
      if (i & 1) pk[i>>1] |= ((unsigned)bv << 16);
      else       pk[i>>1]  = (unsigned)bv;
    }
  }
  size_t rowbase = ((size_t)bid*64 + p)*64 + cg*16;
  uint4 u0; u0.x = pk[0]; u0.y = pk[1]; u0.z = pk[2]; u0.w = pk[3];
  uint4 u1; u1.x = pk[4]; u1.y = pk[5]; u1.z = pk[6]; u1.w = pk[7];
  *(uint4*)(t + rowbase)     = u0;
  *(uint4*)(t + rowbase + 8) = u1;
}

// ---------------- K2: fused GEMM1 -> sample -> GEMM2 (+BN partials) ---------
// om and sval live only in LDS. Channel mapping: sy=om[2c], sx=om[2c+1],
// modulator=om[128+c]. Bias dropped (cancels in BN exactly).
// Phase B lane map: pl=tid&63, cg=tid>>6 -> a coalescing quad holds 4 ADJACENT
// PIXELS of the SAME channel plane.
__global__ __launch_bounds__(256, 5) void k_fuse(
    const unsigned short* __restrict__ xB,
    const unsigned short* __restrict__ t,
    const unsigned short* __restrict__ pwB,
    const unsigned short* __restrict__ w2B,
    unsigned short* __restrict__ outB,
    float* __restrict__ gsumS,
    float* __restrict__ gsqS)
{
  __shared__ __align__(16) char lds[25600];
  unsigned short* OM = (unsigned short*)lds;        // 64 x OMS bf16 (25600 B)
  unsigned short* T  = (unsigned short*)lds;        // 64 x TS bf16 (overlays OM)
  float* red1 = (float*)(lds + 9216);               // 4 x 64 (overlays dead OM tail)
  float* red2 = (float*)(lds + 10240);              // 4 x 64

  int tid = threadIdx.x;
  int bid = ((blockIdx.x & 7) << 9) + (blockIdx.x >> 3);   // XCD-contiguous
  int wv = tid >> 6, lane = tid & 63;
  int mrow = lane & 15, q = lane >> 4;
  int px0 = bid*64;
  int pxw = px0 + wv*16;        // wave's pixel base (16 px per wave)

  // ---- phase A: GEMM1  om[px][ch] = sum_c t[px][c]*pw[ch][c] ----
  short8 bfrag[2];
#pragma unroll
  for (int kb = 0; kb < 2; ++kb)
    bfrag[kb] = *(const short8*)(t + (size_t)(pxw + mrow)*64 + kb*32 + q*8);

  floatx4 acc[12];
#pragma unroll
  for (int mt = 0; mt < 12; ++mt) acc[mt] = (floatx4){0.f,0.f,0.f,0.f};
#pragma unroll
  for (int kb = 0; kb < 2; ++kb)
#pragma unroll
    for (int mt = 0; mt < 12; ++mt){
      short8 af = *(const short8*)(pwB + (mt*16 + mrow)*64 + kb*32 + q*8);
      acc[mt] = __builtin_amdgcn_mfma_f32_16x16x32_bf16(af, bfrag[kb], acc[mt], 0, 0, 0);
    }

  {
    int omrow = (wv*16 + mrow)*OMS;
#pragma unroll
    for (int mt = 0; mt < 12; ++mt){
      uint2 u; u.x = pack2(acc[mt][0], acc[mt][1]); u.y = pack2(acc[mt][2], acc[mt][3]);
      *(uint2*)(OM + omrow + mt*16 + q*4) = u;
    }
  }
  __syncthreads();

  // ---- phase B: deformable bilinear sampling from bf16 x ----
  unsigned pk[8];
  {
    int pl = tid & 63;          // block-local pixel   (quad = 4 adjacent px)
    int cg = tid >> 6;          // channel group       (wave-uniform)
    int px = px0 + pl;
    int b = px >> 16;
    int p = px & (HW_-1);
    int h = p >> 8, w = p & (W_-1);

    const char* xbyte = (const char*)(xB + ((size_t)(b*C_ + cg*16) << 16));
    float hf = (float)h, wf = (float)w;

    float rw0[8], rw1[8], cwA[8], cwB[8];
    unsigned pu0[8], pu1[8];

#pragma unroll
    for (int half = 0; half < 2; ++half){
      const uint4* ob = (const uint4*)(OM + pl*OMS + cg*32 + half*16);
      uint4 oA = ob[0], oB = ob[1];
      uint4 mv = *(const uint4*)(OM + pl*OMS + 128 + cg*16 + half*8);
      unsigned pr[8] = {oA.x,oA.y,oA.z,oA.w, oB.x,oB.y,oB.z,oB.w};
      unsigned md4[4] = {mv.x,mv.y,mv.z,mv.w};

      // ---- stage: addresses + weights, issue the 16 loads ----
#pragma unroll
      for (int i = 0; i < 8; ++i){
        unsigned pair = pr[i];
        float oy = __uint_as_float(pair << 16);
        float ox = __uint_as_float(pair & 0xffff0000u);
        float mm = __uint_as_float((i & 1) ? (md4[i>>1] & 0xffff0000u)
                                           : (md4[i>>1] << 16));
        float mod = 2.f / (1.f + __expf(-mm));
        oy = fminf(fmaxf(oy, -64.f), 64.f);
        ox = fminf(fmaxf(ox, -64.f), 64.f);
        float sy = hf + oy, sx = wf + ox;
        float y0f = floorf(sy), x0f = floorf(sx);
        float wy = sy - y0f, wxr = sx - x0f;
        int y0 = (int)y0f, x0 = (int)x0f;
        int yc0 = min(max(y0,     0), 255);
        int yc1 = min(max(y0 + 1, 0), 255);    // clamp AFTER increment
        int xc  = min(max(x0, 0), 254);        // pair start (always in-plane)
        bool y0v = ((unsigned)y0       < 256u);
        bool y1v = ((unsigned)(y0 + 1) < 256u);
        bool x0v = ((unsigned)x0       < 256u);
        bool x1v = ((unsigned)(x0 + 1) < 256u);
        bool x0lo = (x0 == xc);
        float r0 = y0v ? (1.f - wy) * mod : 0.f;
        float r1 = y1v ? wy * mod : 0.f;
        float c0w = x0v ? (1.f - wxr) : 0.f;
        float c1w = x1v ? wxr : 0.f;
        rw0[i] = r0; rw1[i] = r1;
        cwA[i] = x0lo ? c0w : c1w;             // weight on value at xc
        cwB[i] = x0lo ? c1w : c0w;             // weight on value at xc+1
        unsigned cb  = ((unsigned)(half*8 + i)) << 17;   // channel byte offset
        unsigned o0  = cb + ((unsigned)yc0 << 9) + ((unsigned)xc << 1);
        unsigned o1  = cb + ((unsigned)yc1 << 9) + ((unsigned)xc << 1);
        __builtin_memcpy(&pu0[i], xbyte + o0, 4);   // (y0 row, x: xc..xc+1)
        __builtin_memcpy(&pu1[i], xbyte + o1, 4);   // (y0+1 row, same)
      }
      // ---- consume ----
#pragma unroll
      for (int i = 0; i < 8; ++i){
        int ci = half*8 + i;
        float lo0 = __uint_as_float(pu0[i] << 16);
        float hi0 = __uint_as_float(pu0[i] & 0xffff0000u);
        float lo1 = __uint_as_float(pu1[i] << 16);
        float hi1 = __uint_as_float(pu1[i] & 0xffff0000u);
        float sres = rw0[i] * (cwA[i]*lo0 + cwB[i]*hi0)
                   + rw1[i] * (cwA[i]*lo1 + cwB[i]*hi1);
        unsigned short bv = f2bf(sres);
        if (ci & 1) pk[ci>>1] |= ((unsigned)bv << 16);
        else        pk[ci>>1]  = (unsigned)bv;
      }
    }
  }
  __syncthreads();              // all OM reads done before T overlays it

  {
    int pl = tid & 63, cg = tid >> 6;
    uint4 u0; u0.x = pk[0]; u0.y = pk[1]; u0.z = pk[2]; u0.w = pk[3];
    uint4 u1; u1.x = pk[4]; u1.y = pk[5]; u1.z = pk[6]; u1.w = pk[7];
    *(uint4*)(T + pl*TS + cg*16)     = u0;
    *(uint4*)(T + pl*TS + cg*16 + 8) = u1;
  }
  __syncthreads();

  // ---- phase C: GEMM2  out[px][och] = sum_c sval[px][c]*w2[och][c] ----
  short8 a2[2];
#pragma unroll
  for (int kb = 0; kb < 2; ++kb)
    a2[kb] = *(const short8*)(T + (wv*16 + mrow)*TS + kb*32 + q*8);

  floatx4 acc2[4];
#pragma unroll
  for (int nt = 0; nt < 4; ++nt) acc2[nt] = (floatx4){0.f,0.f,0.f,0.f};
#pragma unroll
  for (int kb = 0; kb < 2; ++kb)
#pragma unroll
    for (int nt = 0; nt < 4; ++nt){
      short8 bf = *(const short8*)(w2B + (nt*16 + mrow)*64 + kb*32 + q*8);
      acc2[nt] = __builtin_amdgcn_mfma_f32_16x16x32_bf16(a2[kb], bf, acc2[nt], 0, 0, 0);
    }

  int b   = pxw >> 16;
  int hw0 = pxw & (HW_-1);
#pragma unroll
  for (int nt = 0; nt < 4; ++nt){
    int och = nt*16 + mrow;
    float a0 = acc2[nt][0], a1 = acc2[nt][1], a2v = acc2[nt][2], a3 = acc2[nt][3];
    uint2 u; u.x = pack2(a0, a1); u.y = pack2(a2v, a3);
    *(uint2*)(outB + ((size_t)(b*C_ + och) << 16) + hw0 + q*4) = u;
    float s1 = a0 + a1 + a2v + a3;
    float s2 = a0*a0 + a1*a1 + a2v*a2v + a3*a3;
    s1 += __shfl_xor(s1, 16, 64);  s2 += __shfl_xor(s2, 16, 64);
    s1 += __shfl_xor(s1, 32, 64);  s2 += __shfl_xor(s2, 32, 64);
    if (q == 0){ red1[wv*64 + och] = s1; red2[wv*64 + och] = s2; }
  }
  __syncthreads();
  if (tid < 64){
    float t1 = red1[tid] + red1[64+tid] + red1[128+tid] + red1[192+tid];
    float t2 = red2[tid] + red2[64+tid] + red2[128+tid] + red2[192+tid];
    int slot = blockIdx.x & 31;
    atomicAdd(&gsumS[slot*64 + tid], t1);
    atomicAdd(&gsqS[slot*64 + tid], t2);
  }
}

// ---------------- finalize BN stats into scale/shift ------------------------
__global__ void k_finalize(const float* __restrict__ gsumS, const float* __restrict__ gsqS,
                           const float* __restrict__ gamma, const float* __restrict__ beta,
                           float* __restrict__ scale, float* __restrict__ shift)
{
  int o = threadIdx.x;
  if (o < 64){
    float s1 = 0.f, s2 = 0.f;
    for (int s = 0; s < 32; ++s){ s1 += gsumS[s*64 + o]; s2 += gsqS[s*64 + o]; }
    float n = (float)NPIX_;
    float mean = s1 / n;
    float var  = s2 / n - mean*mean;          // biased, matches jnp.var
    float sc = gamma[o] * rsqrtf(var + 1e-5f);
    scale[o] = sc;
    shift[o] = beta[o] - mean*sc;
  }
}

// ---------------- K5: BN apply + exact GELU, 8 elems/thread -----------------
__global__ __launch_bounds__(256) void k_bn_gelu(
    const uint4* __restrict__ outB4,   // 8 bf16
    const float* __restrict__ scale,
    const float* __restrict__ shift,
    float4* __restrict__ y4)
{
  int i = blockIdx.x*256 + threadIdx.x;           // over NELEM_/8
  int och = (i >> 13) & 63;                       // (8i >> 16) & 63
  float sc = scale[och], sh = shift[och];
  uint4 u = outB4[i];
  float e[8];
  e[0] = bf2f((unsigned short)(u.x & 0xffffu)); e[1] = bf2f((unsigned short)(u.x >> 16));
  e[2] = bf2f((unsigned short)(u.y & 0xffffu)); e[3] = bf2f((unsigned short)(u.y >> 16));
  e[4] = bf2f((unsigned short)(u.z & 0xffffu)); e[5] = bf2f((unsigned short)(u.z >> 16));
  e[6] = bf2f((unsigned short)(u.w & 0xffffu)); e[7] = bf2f((unsigned short)(u.w >> 16));
  float4 o0, o1;
  float a;
  a = e[0]*sc + sh; o0.x = 0.5f*a*(1.f + erff(a*0.70710678118654752f));
  a = e[1]*sc + sh; o0.y = 0.5f*a*(1.f + erff(a*0.70710678118654752f));
  a = e[2]*sc + sh; o0.z = 0.5f*a*(1.f + erff(a*0.70710678118654752f));
  a = e[3]*sc + sh; o0.w = 0.5f*a*(1.f + erff(a*0.70710678118654752f));
  a = e[4]*sc + sh; o1.x = 0.5f*a*(1.f + erff(a*0.70710678118654752f));
  a = e[5]*sc + sh; o1.y = 0.5f*a*(1.f + erff(a*0.70710678118654752f));
  a = e[6]*sc + sh; o1.z = 0.5f*a*(1.f + erff(a*0.70710678118654752f));
  a = e[7]*sc + sh; o1.w = 0.5f*a*(1.f + erff(a*0.70710678118654752f));
  y4[2*i]   = o0;
  y4[2*i+1] = o1;
}

extern "C" void kernel_launch(void* const* d_in, const int* in_sizes, int n_in,
                              void* d_out, int out_size, void* d_ws, size_t ws_size,
                              hipStream_t stream)
{
  (void)in_sizes; (void)n_in; (void)out_size; (void)ws_size;
  const float* x     = (const float*)d_in[0];
  const float* dw    = (const float*)d_in[1];
  const float* pw    = (const float*)d_in[2];
  const float* w2    = (const float*)d_in[3];
  /* d_in[4] = bias: cancels exactly in BN (mean-subtracted), unused */
  const float* gamma = (const float*)d_in[5];
  const float* beta  = (const float*)d_in[6];

  // ws layout:
  //   [0,          33554432)  xB    bf16 x
  //   [33554432,   67108864)  t     bf16 dwconv out [px][c]
  //   [67108864,  100663296)  outB  bf16 conv2 out, och-major
  //   [100663296, 100680192)  stats (gsumS 8K, gsqS 8K, scale/shift)
  //   [100680192, 100712960)  wB    bf16 weights (pw 24K, w2 8K)
  char* ws = (char*)d_ws;
  unsigned short* xB    = (unsigned short*)ws;
  unsigned short* t     = (unsigned short*)(ws + 33554432);
  unsigned short* outB  = (unsigned short*)(ws + 67108864);
  float*          stats = (float*)(ws + 100663296);
  float* gsumS = stats;                 // 32 slots x 64
  float* gsqS  = stats + 2048;
  float* scale = stats + 4096;
  float* shift = stats + 4160;
  unsigned short* wB  = (unsigned short*)(ws + 100680192);
  unsigned short* pwB = wB;
  unsigned short* w2B = wB + 12288;

  k_cvtw    <<<64, 256, 0, stream>>>(pw, w2, wB);
  hipMemsetAsync(stats, 0, 16384, stream);        // zero gsum/gsq slots
  k_dwconv  <<<NPIX_/64, 256, 0, stream>>>(x, dw, xB, t);
  k_fuse    <<<NPIX_/64, 256, 0, stream>>>(xB, t, pwB, w2B, outB, gsumS, gsqS);
  k_finalize<<<1, 64, 0, stream>>>(gsumS, gsqS, gamma, beta, scale, shift);
  k_bn_gelu <<<NELEM_/8/256, 256, 0, stream>>>((const uint4*)outB, scale, shift,
                                               (float4*)d_out);
}